// Round 3
// baseline (789.713 us; speedup 1.0000x reference)
//
#include <hip/hip_runtime.h>
#include <hip/hip_bf16.h>

#define B_ 32
#define PS_ 1536
#define TNS_ 2048
#define NJ_ 128
#define QK_ 384
#define NC_ 200
#define BN_EPS_ 1e-5f

typedef __attribute__((ext_vector_type(8))) short short8;
typedef __attribute__((ext_vector_type(4))) float float4v;
typedef unsigned short ushort_t;

__device__ __forceinline__ unsigned short f2b(float f) {
    unsigned int u = __float_as_uint(f);
    return (unsigned short)((u + 0x7FFFu + ((u >> 16) & 1u)) >> 16);
}
__device__ __forceinline__ float b2f_lo(unsigned int u) { return __uint_as_float(u << 16); }
__device__ __forceinline__ float b2f_hi(unsigned int u) { return __uint_as_float(u & 0xffff0000u); }

// ------------- MFMA tile machinery: 128x128 block, BK=64, 4 waves -----------
// LDS rows padded 64->72 shorts (144 B) to avoid bank conflicts on ds_read_b128
__device__ __forceinline__ void mma_chunk(const short* As, const short* Bs,
                                          int wm, int wn, int lane, float4v acc[4][4]) {
    const int m0 = wm + (lane & 15);
    const int n0 = wn + (lane & 15);
    const int quad = lane >> 4;
    #pragma unroll
    for (int kk = 0; kk < 64; kk += 32) {
        short8 a[4], b[4];
        const int kb = quad * 8 + kk;
        #pragma unroll
        for (int i = 0; i < 4; ++i) {
            a[i] = *(const short8*)&As[(m0 + i * 16) * 72 + kb];
            b[i] = *(const short8*)&Bs[(n0 + i * 16) * 72 + kb];
        }
        #pragma unroll
        for (int i = 0; i < 4; ++i)
            #pragma unroll
            for (int j = 0; j < 4; ++j)
                acc[i][j] = __builtin_amdgcn_mfma_f32_16x16x32_bf16(a[i], b[j], acc[i][j], 0, 0, 0);
    }
}

// ---- staging split into global->regs and regs->LDS for VGPR double-buffer --
__device__ __forceinline__ void load_f32(const float* __restrict__ src, size_t stride,
                                         int tid, float4 r[8]) {
    #pragma unroll
    for (int p = 0; p < 8; ++p) {
        int row = (tid >> 4) + p * 16;
        int kq = (tid & 15) * 4;
        r[p] = *(const float4*)(src + (size_t)row * stride + kq);
    }
}
__device__ __forceinline__ void write_f32(const float4 r[8], short* dst, int tid) {
    #pragma unroll
    for (int p = 0; p < 8; ++p) {
        int row = (tid >> 4) + p * 16;
        int kq = (tid & 15) * 4;
        ushort4 u = { f2b(r[p].x), f2b(r[p].y), f2b(r[p].z), f2b(r[p].w) };
        *(ushort4*)&dst[row * 72 + kq] = u;
    }
}
__device__ __forceinline__ void load_b16(const ushort_t* __restrict__ src, size_t stride,
                                         int tid, uint4 r[4]) {
    #pragma unroll
    for (int p = 0; p < 4; ++p) {
        int row = (tid >> 3) + p * 32;
        int kq = (tid & 7) * 8;
        r[p] = *(const uint4*)(src + (size_t)row * stride + kq);
    }
}
__device__ __forceinline__ void write_b16(const uint4 r[4], short* dst, int tid) {
    #pragma unroll
    for (int p = 0; p < 4; ++p) {
        int row = (tid >> 3) + p * 32;
        int kq = (tid & 7) * 8;
        *(uint4*)&dst[row * 72 + kq] = r[p];
    }
}

// ---------------- fused prep: wq/wk col-means, scalars, bf16 converts -------
__global__ void k_prep_all(const float* __restrict__ wq, const float* __restrict__ bq,
                           const float* __restrict__ wk, const float* __restrict__ bk,
                           const float* __restrict__ wp1,
                           const float* __restrict__ w_pool0, const float* __restrict__ w_c1,
                           float* __restrict__ wqb, float* __restrict__ wkb,
                           float* __restrict__ scal,
                           ushort_t* __restrict__ w0b, ushort_t* __restrict__ wc1b) {
    const int blk = blockIdx.x;
    const int tid = threadIdx.x;
    if (blk < 6) {
        int c = blk * 256 + tid;
        float s = 0.f;
        for (int o = 0; o < QK_; ++o) s += wq[(size_t)o * PS_ + c];
        wqb[c] = s * (1.0f / QK_);
    } else if (blk < 12) {
        int c = (blk - 6) * 256 + tid;
        float s = 0.f;
        for (int o = 0; o < QK_; ++o) s += wk[(size_t)o * PS_ + c];
        wkb[c] = s * (1.0f / QK_);
    } else if (blk == 12) {
        __shared__ float red[256];
        float s = (tid < QK_ ? bq[tid] : 0.f) + (tid + 256 < QK_ ? bq[tid + 256] : 0.f);
        red[tid] = s; __syncthreads();
        for (int off = 128; off > 0; off >>= 1) { if (tid < off) red[tid] += red[tid + off]; __syncthreads(); }
        if (tid == 0) scal[0] = red[0] * (1.0f / QK_);
        __syncthreads();
        s = (tid < QK_ ? bk[tid] : 0.f) + (tid + 256 < QK_ ? bk[tid + 256] : 0.f);
        red[tid] = s; __syncthreads();
        for (int off = 128; off > 0; off >>= 1) { if (tid < off) red[tid] += red[tid + off]; __syncthreads(); }
        if (tid == 0) scal[1] = red[0] * (1.0f / QK_);
        __syncthreads();
        s = (tid < NJ_ ? wp1[tid] : 0.f);
        red[tid] = s; __syncthreads();
        for (int off = 128; off > 0; off >>= 1) { if (tid < off) red[tid] += red[tid + off]; __syncthreads(); }
        if (tid == 0) scal[2] = red[0];
    } else if (blk < 13 + 256) {
        int i = (blk - 13) * 256 + tid;   // w_pool0: 65536 float4
        float4 v = ((const float4*)w_pool0)[i];
        ushort4 u = { f2b(v.x), f2b(v.y), f2b(v.z), f2b(v.w) };
        ((ushort4*)w0b)[i] = u;
    } else {
        int i = (blk - 269) * 256 + tid;  // w_c1: 589824 float4
        float4 v = ((const float4*)w_c1)[i];
        ushort4 u = { f2b(v.x), f2b(v.y), f2b(v.z), f2b(v.w) };
        ((ushort4*)wc1b)[i] = u;
    }
}

// ---------------- GEMM1: hsT[b][j][c] = sum_s x[(b,c),s]*w0[j,s] + b0[j] ----
__global__ __launch_bounds__(256) void k_gemm1(const float* __restrict__ x,
        const ushort_t* __restrict__ w0b, const float* __restrict__ b0,
        ushort_t* __restrict__ hsT) {
    __shared__ __align__(16) short As[128 * 72];
    __shared__ __align__(16) short Bs[128 * 72];
    const int tid = threadIdx.x, lane = tid & 63, wave = tid >> 6;
    const int wm = (wave >> 1) * 64, wn = (wave & 1) * 64;
    const size_t m0 = (size_t)blockIdx.x * 128;
    float4v acc[4][4] = {};
    float4 aR[8];
    uint4  bR[4];
    load_f32(x + m0 * TNS_, TNS_, tid, aR);
    load_b16(w0b, TNS_, tid, bR);
    for (int k0 = 0; k0 < TNS_; k0 += 64) {
        write_f32(aR, As, tid);
        write_b16(bR, Bs, tid);
        __syncthreads();
        if (k0 + 64 < TNS_) {
            load_f32(x + m0 * TNS_ + k0 + 64, TNS_, tid, aR);
            load_b16(w0b + k0 + 64, TNS_, tid, bR);
        }
        mma_chunk(As, Bs, wm, wn, lane, acc);
        __syncthreads();
    }
    const int b = blockIdx.x / 12, cb = (blockIdx.x % 12) * 128;
    const int quad = lane >> 4;
    #pragma unroll
    for (int jn = 0; jn < 4; ++jn) {
        int j = wn + jn * 16 + (lane & 15);
        float bj = b0[j];
        #pragma unroll
        for (int im = 0; im < 4; ++im) {
            int c = cb + wm + im * 16 + quad * 4;
            float4v v = acc[im][jn];
            ushort4 u = { f2b(v[0] + bj), f2b(v[1] + bj), f2b(v[2] + bj), f2b(v[3] + bj) };
            *(ushort4*)&hsT[((size_t)(b * NJ_ + j)) * PS_ + c] = u;
        }
    }
}

// ---------------- q1/k1 from hsT: contiguous bf16 dot over c ---------------
__global__ __launch_bounds__(256) void k_q1k1(const ushort_t* __restrict__ hsT,
        const float* __restrict__ wqb, const float* __restrict__ wkb,
        float* __restrict__ q1, float* __restrict__ k1) {
    int wid = blockIdx.x * 4 + (threadIdx.x >> 6);
    int lane = threadIdx.x & 63;
    int b = wid >> 7, j = wid & 127;
    const unsigned int* row = (const unsigned int*)(hsT + ((size_t)(b * NJ_ + j)) * PS_);
    float sq = 0.f, sk = 0.f;
    #pragma unroll
    for (int i = 0; i < 12; ++i) {
        unsigned int u = row[i * 64 + lane];
        int c = (i * 64 + lane) * 2;
        float v0 = b2f_lo(u), v1 = b2f_hi(u);
        sq += wqb[c] * v0 + wqb[c + 1] * v1;
        sk += wkb[c] * v0 + wkb[c + 1] * v1;
    }
    #pragma unroll
    for (int off = 32; off > 0; off >>= 1) { sq += __shfl_down(sq, off, 64); sk += __shfl_down(sk, off, 64); }
    if (lane == 0) { q1[b * NJ_ + j] = sq; k1[b * NJ_ + j] = sk; }
}

// ---------------- A1t[b][j2][j] = adj[j][j2] + tanh(q1[j]-k1[j2])*alpha ----
__global__ void k_a1(const float* __restrict__ adj, const float* __restrict__ q1,
                     const float* __restrict__ k1, const float* __restrict__ alpha,
                     const float* __restrict__ scal, ushort_t* __restrict__ A1t) {
    int idx = blockIdx.x * 256 + threadIdx.x;   // b*16384 + j2*128 + j
    int b = idx >> 14;
    int r = idx & 16383;
    int j2 = r >> 7;
    int j = r & 127;
    float dbias = scal[0] - scal[1];
    float t = tanhf(q1[b * NJ_ + j] - k1[b * NJ_ + j2] + dbias);
    A1t[idx] = f2b(adj[j * NJ_ + j2] + t * alpha[0]);
}

// ---------------- GEMM2: hs2[b][o][j] = sum_c wc1[o][c]*hsT[b][j][c]+bc1[o] -
__global__ __launch_bounds__(256) void k_gemm2(const ushort_t* __restrict__ wc1b,
        const float* __restrict__ bc1, const ushort_t* __restrict__ hsT,
        ushort_t* __restrict__ hs2) {
    __shared__ __align__(16) short As[128 * 72];
    __shared__ __align__(16) short Bs[128 * 72];
    const int tid = threadIdx.x, lane = tid & 63, wave = tid >> 6;
    const int wm = (wave >> 1) * 64, wn = (wave & 1) * 64;
    const int b = blockIdx.y, ob = blockIdx.x * 128;
    float4v acc[4][4] = {};
    const ushort_t* Abase = wc1b + (size_t)ob * PS_;
    const ushort_t* Bbase = hsT + (size_t)b * NJ_ * PS_;
    uint4 aR[4], bR[4];
    load_b16(Abase, PS_, tid, aR);
    load_b16(Bbase, PS_, tid, bR);
    for (int k0 = 0; k0 < PS_; k0 += 64) {
        write_b16(aR, As, tid);
        write_b16(bR, Bs, tid);
        __syncthreads();
        if (k0 + 64 < PS_) {
            load_b16(Abase + k0 + 64, PS_, tid, aR);
            load_b16(Bbase + k0 + 64, PS_, tid, bR);
        }
        mma_chunk(As, Bs, wm, wn, lane, acc);
        __syncthreads();
    }
    const int quad = lane >> 4;
    #pragma unroll
    for (int im = 0; im < 4; ++im) {
        int o0 = ob + wm + im * 16 + quad * 4;
        float bc[4] = { bc1[o0], bc1[o0 + 1], bc1[o0 + 2], bc1[o0 + 3] };
        #pragma unroll
        for (int jn = 0; jn < 4; ++jn) {
            int j = wn + jn * 16 + (lane & 15);
            float4v v = acc[im][jn];
            #pragma unroll
            for (int r = 0; r < 4; ++r)
                hs2[((size_t)(b * PS_) + o0 + r) * NJ_ + j] = f2b(v[r] + bc[r]);
        }
    }
}

// -------- GEMM3 + fused BN stats: hs3[b][c][j2] = sum_j hs2[b][c][j]*A1t ---
__global__ __launch_bounds__(256) void k_gemm3(const ushort_t* __restrict__ hs2,
        const ushort_t* __restrict__ A1t, ushort_t* __restrict__ hs3b,
        float* __restrict__ bnsum, float* __restrict__ bnsq) {
    __shared__ __align__(16) short As[128 * 72];
    __shared__ __align__(16) short Bs[128 * 72];
    const int tid = threadIdx.x, lane = tid & 63, wave = tid >> 6;
    const int wm = (wave >> 1) * 64, wn = (wave & 1) * 64;
    const int b = blockIdx.y, cbs = blockIdx.x * 128;
    float4v acc[4][4] = {};
    const ushort_t* Abase = hs2 + ((size_t)(b * PS_) + cbs) * NJ_;
    const ushort_t* Bbase = A1t + (size_t)b * NJ_ * NJ_;
    uint4 aR[4], bR[4];
    load_b16(Abase, NJ_, tid, aR);
    load_b16(Bbase, NJ_, tid, bR);
    for (int k0 = 0; k0 < NJ_; k0 += 64) {
        write_b16(aR, As, tid);
        write_b16(bR, Bs, tid);
        __syncthreads();
        if (k0 + 64 < NJ_) {
            load_b16(Abase + k0 + 64, NJ_, tid, aR);
            load_b16(Bbase + k0 + 64, NJ_, tid, bR);
        }
        mma_chunk(As, Bs, wm, wn, lane, acc);
        __syncthreads();
    }
    const int quad = lane >> 4;
    #pragma unroll
    for (int im = 0; im < 4; ++im) {
        int c0 = cbs + wm + im * 16 + quad * 4;
        float s[4] = {0.f, 0.f, 0.f, 0.f}, q[4] = {0.f, 0.f, 0.f, 0.f};
        #pragma unroll
        for (int jn = 0; jn < 4; ++jn) {
            int j2 = wn + jn * 16 + (lane & 15);
            float4v v = acc[im][jn];
            #pragma unroll
            for (int r = 0; r < 4; ++r) {
                hs3b[((size_t)(b * PS_) + c0 + r) * NJ_ + j2] = f2b(v[r]);
                s[r] += v[r];
                q[r] += v[r] * v[r];
            }
        }
        #pragma unroll
        for (int r = 0; r < 4; ++r) {
            #pragma unroll
            for (int off = 8; off > 0; off >>= 1) {
                s[r] += __shfl_down(s[r], off, 16);
                q[r] += __shfl_down(q[r], off, 16);
            }
        }
        if ((lane & 15) == 0) {
            #pragma unroll
            for (int r = 0; r < 4; ++r) {
                atomicAdd(&bnsum[c0 + r], s[r]);
                atomicAdd(&bnsq[c0 + r], q[r]);
            }
        }
    }
}

// ---------------- BN fold + pool1: p[b,c] ----------------------------------
__global__ void k_pool(const ushort_t* __restrict__ hs3b, const float* __restrict__ bnsum,
                       const float* __restrict__ bnsq, const float* __restrict__ gamma,
                       const float* __restrict__ beta, const float* __restrict__ wp1,
                       const float* __restrict__ bp1, const float* __restrict__ scal,
                       float* __restrict__ p) {
    int gid = blockIdx.x * 256 + threadIdx.x;
    int row = gid >> 6;            // b*PS + c
    int lane = gid & 63;
    int c = row % PS_;
    const unsigned int* hp = (const unsigned int*)(hs3b + (size_t)row * NJ_);
    unsigned int u = hp[lane];
    float d = wp1[2 * lane] * b2f_lo(u) + wp1[2 * lane + 1] * b2f_hi(u);
    #pragma unroll
    for (int off = 32; off > 0; off >>= 1) d += __shfl_down(d, off, 64);
    if (lane == 0) {
        float mean = bnsum[c] * (1.0f / 4096.0f);
        float var = bnsq[c] * (1.0f / 4096.0f) - mean * mean;
        float s = gamma[c] * rsqrtf(var + BN_EPS_);
        p[row] = s * d + (beta[c] - s * mean) * scal[2] + bp1[0];
    }
}

// ---------------- classifier ----------------------------------------------
__global__ void k_cls(const float* __restrict__ p, const float* __restrict__ wcls,
                      const float* __restrict__ bcls, float* __restrict__ out) {
    int gid = blockIdx.x * 256 + threadIdx.x;
    int w = gid >> 6;              // 0..6399
    int lane = gid & 63;
    int b = w / 200, n = w % 200;
    const float* pp = p + (size_t)b * PS_;
    const float* wp = wcls + (size_t)n * PS_;
    float s = 0.f;
    for (int c = lane; c < PS_; c += 64) s += pp[c] * wp[c];
    #pragma unroll
    for (int off = 32; off > 0; off >>= 1) s += __shfl_down(s, off, 64);
    if (lane == 0) out[w] = s + bcls[n];
}

extern "C" void kernel_launch(void* const* d_in, const int* in_sizes, int n_in,
                              void* d_out, int out_size, void* d_ws, size_t ws_size,
                              hipStream_t stream) {
    const float* x       = (const float*)d_in[0];
    const float* w_pool0 = (const float*)d_in[1];
    const float* b_pool0 = (const float*)d_in[2];
    const float* adj1    = (const float*)d_in[3];
    const float* w_q     = (const float*)d_in[4];
    const float* b_q     = (const float*)d_in[5];
    const float* w_k     = (const float*)d_in[6];
    const float* b_k     = (const float*)d_in[7];
    const float* alpha   = (const float*)d_in[8];
    const float* w_c1    = (const float*)d_in[9];
    const float* b_c1    = (const float*)d_in[10];
    const float* gamma   = (const float*)d_in[11];
    const float* beta    = (const float*)d_in[12];
    const float* w_pool1 = (const float*)d_in[13];
    const float* b_pool1 = (const float*)d_in[14];
    const float* w_cls   = (const float*)d_in[15];
    const float* b_cls   = (const float*)d_in[16];
    float* out = (float*)d_out;

    // workspace layout
    ushort_t* hsT  = (ushort_t*)d_ws;          // 6,291,456 bf16 (B*NJ x PS)
    ushort_t* hs2  = hsT + 6291456;            // 6,291,456 bf16 (B*PS x NJ)
    ushort_t* hs3b = hs2 + 6291456;            // 6,291,456 bf16 (B*PS x NJ)
    ushort_t* w0b  = hs3b + 6291456;           // 262,144 bf16
    ushort_t* wc1b = w0b + 262144;             // 2,359,296 bf16
    ushort_t* A1t  = wc1b + 2359296;           // 524,288 bf16
    float* fb    = (float*)(A1t + 524288);
    float* wqb   = fb;                         // 1536
    float* wkb   = wqb + 1536;                 // 1536
    float* scal  = wkb + 1536;                 // 16
    float* q1    = scal + 16;                  // 4096
    float* k1    = q1 + 4096;                  // 4096
    float* bnsum = k1 + 4096;                  // 1536
    float* bnsq  = bnsum + 1536;               // 1536
    float* pbuf  = bnsq + 1536;                // 49152
    size_t need = 44040192u + (size_t)(1536 + 1536 + 16 + 4096 + 4096 + 1536 + 1536 + 49152) * 4;
    if (ws_size < need) return;

    // zero BN atomic accumulators (bnsum, bnsq contiguous)
    hipMemsetAsync((void*)bnsum, 0, (1536 + 1536) * sizeof(float), stream);

    k_prep_all<<<2573, 256, 0, stream>>>(w_q, b_q, w_k, b_k, w_pool1, w_pool0, w_c1,
                                         wqb, wkb, scal, w0b, wc1b);
    k_gemm1<<<384, 256, 0, stream>>>(x, w0b, b_pool0, hsT);
    k_q1k1 <<<1024, 256, 0, stream>>>(hsT, wqb, wkb, q1, k1);
    k_a1   <<<2048, 256, 0, stream>>>(adj1, q1, k1, alpha, scal, A1t);
    k_gemm2<<<dim3(12, 32), 256, 0, stream>>>(wc1b, b_c1, hsT, hs2);
    k_gemm3<<<dim3(12, 32), 256, 0, stream>>>(hs2, A1t, hs3b, bnsum, bnsq);
    k_pool <<<12288, 256, 0, stream>>>(hs3b, bnsum, bnsq, gamma, beta, w_pool1, b_pool1, scal, pbuf);
    k_cls  <<<1600, 256, 0, stream>>>(pbuf, w_cls, b_cls, out);
}